// Round 5
// baseline (46.421 us; speedup 1.0000x reference)
//
#include <hip/hip_runtime.h>
#include <hip/hip_bf16.h>

// Sizes from the reference
#define BATCH   128
#define SEQ_T   64
#define SEQ_A   1024
#define SEQ_V   512
#define D_T     768
#define D_AV    256
#define DST_LEN 64

// Column-split factors (blocks per output row) — bounds the worst-case
// per-block stream (ml=1 concentrates a sample's whole input in one row).
#define CS_A 4
#define CS_V 2
#define NB_A (BATCH * DST_LEN * CS_A)   // 32768
#define NB_V (BATCH * DST_LEN * CS_V)   // 16384
#define NB_COPY 1536                    // 1,572,864 float4 / (256 thr * 4 f4)

__device__ __forceinline__ void add4(float4& a, const float4 v) {
    a.x += v.x; a.y += v.y; a.z += v.z; a.w += v.w;
}

// ---------------------------------------------------------------------------
// One of CS blocks computing output row (b, j): this block owns float4
// columns [cs*CHUNKS, (cs+1)*CHUNKS). 256 threads = RSLOTS row-slots x
// CHUNKS columns; thread (r,c) strides the pooling window by RSLOTS rows
// with 8 independent accumulators (32KB of loads in flight per block).
// LDS-reduce across row-slots, then one coalesced 16B store per column.
// ---------------------------------------------------------------------------
template<int CS>
__device__ __forceinline__ void align_row_cs(const float* __restrict__ x,
                                             const int* __restrict__ text_len,
                                             const int* __restrict__ lengths,
                                             float* __restrict__ out,
                                             int T, int pair, int cs) {
    constexpr int CHUNKS = 64 / CS;       // float4 columns per block
    constexpr int RSLOTS = 256 / CHUNKS;  // parallel row slots
    const int b   = pair >> 6;            // 64 rows per sample
    const int j   = pair & 63;
    const int tid = threadIdx.x;
    const int r   = tid / CHUNKS;
    const int c   = tid % CHUNKS;
    const int col = cs * CHUNKS + c;      // global float4 column 0..63

    const int ml  = text_len[b] - 2;      // min_len in [1, 63]
    const int len = lengths[b];

    if (j < 1 || j > ml) {                // zero row: cs 0 writes, rest exit
        if (cs == 0 && tid < 64) {
            float4* __restrict__ orow =
                (float4*)(out + ((size_t)b * DST_LEN + j) * D_AV);
            orow[tid] = make_float4(0.f, 0.f, 0.f, 0.f);
        }
        return;
    }

    const unsigned ps = (unsigned)(len + ml - 1) / (unsigned)ml;
    const float inv = 1.0f / (float)ps;
    const int lo = (j - 1) * (int)ps;
    int hi = j * (int)ps;
    if (hi > len) hi = len;

    const float4* __restrict__ xb =
        (const float4*)(x + (size_t)b * (size_t)T * D_AV);

    float4 a0 = make_float4(0.f, 0.f, 0.f, 0.f);
    float4 a1 = a0, a2 = a0, a3 = a0, a4 = a0, a5 = a0, a6 = a0, a7 = a0;

    int t = lo + r;
    for (; t + 7 * RSLOTS < hi; t += 8 * RSLOTS) {
        float4 v0 = xb[(size_t)(t             ) * 64 + col];
        float4 v1 = xb[(size_t)(t + 1 * RSLOTS) * 64 + col];
        float4 v2 = xb[(size_t)(t + 2 * RSLOTS) * 64 + col];
        float4 v3 = xb[(size_t)(t + 3 * RSLOTS) * 64 + col];
        float4 v4 = xb[(size_t)(t + 4 * RSLOTS) * 64 + col];
        float4 v5 = xb[(size_t)(t + 5 * RSLOTS) * 64 + col];
        float4 v6 = xb[(size_t)(t + 6 * RSLOTS) * 64 + col];
        float4 v7 = xb[(size_t)(t + 7 * RSLOTS) * 64 + col];
        add4(a0, v0); add4(a1, v1); add4(a2, v2); add4(a3, v3);
        add4(a4, v4); add4(a5, v5); add4(a6, v6); add4(a7, v7);
    }
    for (; t < hi; t += RSLOTS)
        add4(a0, xb[(size_t)t * 64 + col]);

    add4(a0, a1); add4(a2, a3); add4(a4, a5); add4(a6, a7);
    add4(a0, a2); add4(a4, a6); add4(a0, a4);

    __shared__ float4 red[RSLOTS][CHUNKS];
    red[r][c] = a0;                       // tid-linear -> conflict-free
    __syncthreads();
    if (tid < CHUNKS) {
        float4 s = make_float4(0.f, 0.f, 0.f, 0.f);
        #pragma unroll
        for (int rr = 0; rr < RSLOTS; ++rr)
            add4(s, red[rr][tid]);
        s.x *= inv; s.y *= inv; s.z *= inv; s.w *= inv;
        float4* __restrict__ orow =
            (float4*)(out + ((size_t)b * DST_LEN + j) * D_AV);
        orow[cs * CHUNKS + tid] = s;
    }
}

// Grid layout (256-thread blocks): heavy align sections first, copy last.
//   [0, NB_A)            : audio, block = pair*CS_A + cs
//   [NB_A, +NB_V)        : video, block = pair*CS_V + cs
//   [NB_A+NB_V, +NB_COPY): text passthrough, 4 float4 per thread
__global__ __launch_bounds__(256)
void fused_align_kernel(const float4* __restrict__ text_in,
                        float4* __restrict__ text_out,
                        const float* __restrict__ audio_x,
                        const float* __restrict__ video_x,
                        const int* __restrict__ text_lengths,
                        const int* __restrict__ audio_lengths,
                        const int* __restrict__ video_lengths,
                        float* __restrict__ out_audio,
                        float* __restrict__ out_video) {
    const int blk = blockIdx.x;
    if (blk < NB_A) {
        align_row_cs<CS_A>(audio_x, text_lengths, audio_lengths, out_audio,
                           SEQ_A, blk / CS_A, blk % CS_A);
    } else if (blk < NB_A + NB_V) {
        const int k = blk - NB_A;
        align_row_cs<CS_V>(video_x, text_lengths, video_lengths, out_video,
                           SEQ_V, k / CS_V, k % CS_V);
    } else {
        const int base = (blk - NB_A - NB_V) * 1024 + threadIdx.x;
        #pragma unroll
        for (int k = 0; k < 4; ++k)
            text_out[base + k * 256] = text_in[base + k * 256];
    }
}

extern "C" void kernel_launch(void* const* d_in, const int* in_sizes, int n_in,
                              void* d_out, int out_size, void* d_ws, size_t ws_size,
                              hipStream_t stream) {
    const float* text_x  = (const float*)d_in[0];
    const float* audio_x = (const float*)d_in[1];
    const float* video_x = (const float*)d_in[2];
    const int* text_lengths  = (const int*)d_in[3];
    const int* audio_lengths = (const int*)d_in[4];
    const int* video_lengths = (const int*)d_in[5];

    float* out = (float*)d_out;
    float* out_text  = out;                                        // B*64*768
    float* out_audio = out_text  + (size_t)BATCH * SEQ_T * D_T;    // B*64*256
    float* out_video = out_audio + (size_t)BATCH * DST_LEN * D_AV; // B*64*256

    const int blocks = NB_A + NB_V + NB_COPY;                      // 50,688
    fused_align_kernel<<<blocks, 256, 0, stream>>>(
        (const float4*)text_x, (float4*)out_text,
        audio_x, video_x,
        text_lengths, audio_lengths, video_lengths,
        out_audio, out_video);
}

// Round 6
// 30.974 us; speedup vs baseline: 1.4987x; 1.4987x over previous
//
#include <hip/hip_runtime.h>
#include <hip/hip_bf16.h>

// Sizes from the reference
#define BATCH   128
#define SEQ_T   64
#define SEQ_A   1024
#define SEQ_V   512
#define D_T     768
#define D_AV    256
#define DST_LEN 64

#define NB_COPY 1536   // 1,572,864 float4 / (256 thr * 4 f4)
#define NB_AV   (BATCH * DST_LEN)   // 8192 blocks per modality

__device__ __forceinline__ void add4(float4& a, const float4 v) {
    a.x += v.x; a.y += v.y; a.z += v.z; a.w += v.w;
}

// ---------------------------------------------------------------------------
// One block per (b, j).  For j in [1, ml]: primary block, computes column
// slice 0 of output row j.  For j > ml (normally a zero row): the block first
// writes zeros to its own row j, then — if the sample's windows are large
// (ps>=48) — doubles as a helper computing column slice s of row jj, where
// s=(j-1)/ml, jj=j-s*ml.  Slices are disjoint column ranges -> no atomics.
//   NS=4 (ps>=128): 16 f4 cols x 16 row slots per block
//   NS=2 (ps>=48):  32 f4 cols x  8 row slots
//   NS=1 (typical): 64 f4 cols x  4 row slots  == round-4 bulk path
// 8 independent accumulators -> 8 loads in flight per thread.
// ---------------------------------------------------------------------------
__device__ __forceinline__ void align_row(const float* __restrict__ x,
                                          const int* __restrict__ text_len,
                                          const int* __restrict__ lengths,
                                          float* __restrict__ out,
                                          int T, int idx) {
    const int b   = idx >> 6;          // 64 rows per sample
    const int j   = idx & 63;
    const int tid = threadIdx.x;

    const int ml  = text_len[b] - 2;   // min_len in [1, 63]
    const int len = lengths[b];

    const unsigned ps = (unsigned)(len + ml - 1) / (unsigned)ml;
    const int k  = (ps >= 128u) ? 2 : (ps >= 48u) ? 1 : 0;  // log2(NS)
    const int NS = 1 << k;

    int jj, s;
    if (j >= 1 && j <= ml) {
        jj = j; s = 0;                 // primary
    } else {
        // zero own row (row 0 and rows > ml are zero rows)
        if (tid < 64) {
            float4* __restrict__ oz =
                (float4*)(out + ((size_t)b * DST_LEN + j) * D_AV);
            oz[tid] = make_float4(0.f, 0.f, 0.f, 0.f);
        }
        if (j == 0) return;
        s  = (j - 1) / ml;             // >= 1, block-uniform
        jj = j - s * ml;               // 1..ml
        if (s >= NS) return;           // no helper role, block-uniform exit
    }

    const int cols = 64 >> k;          // f4 columns this block owns
    const int r    = tid >> (6 - k);   // row slot 0..(4<<k)-1
    const int c    = tid & (cols - 1);
    const int col  = s * cols + c;     // global f4 column
    const int slots = 4 << k;

    const float inv = 1.0f / (float)ps;
    const int lo = (jj - 1) * (int)ps;
    int hi = jj * (int)ps;
    if (hi > len) hi = len;

    const float4* __restrict__ xb =
        (const float4*)(x + (size_t)b * (size_t)T * D_AV);

    float4 a0 = make_float4(0.f, 0.f, 0.f, 0.f);
    float4 a1 = a0, a2 = a0, a3 = a0, a4 = a0, a5 = a0, a6 = a0, a7 = a0;

    int t = lo + r;
    for (; t + 7 * slots < hi; t += 8 * slots) {
        float4 v0 = xb[(size_t)(t            ) * 64 + col];
        float4 v1 = xb[(size_t)(t + 1 * slots) * 64 + col];
        float4 v2 = xb[(size_t)(t + 2 * slots) * 64 + col];
        float4 v3 = xb[(size_t)(t + 3 * slots) * 64 + col];
        float4 v4 = xb[(size_t)(t + 4 * slots) * 64 + col];
        float4 v5 = xb[(size_t)(t + 5 * slots) * 64 + col];
        float4 v6 = xb[(size_t)(t + 6 * slots) * 64 + col];
        float4 v7 = xb[(size_t)(t + 7 * slots) * 64 + col];
        add4(a0, v0); add4(a1, v1); add4(a2, v2); add4(a3, v3);
        add4(a4, v4); add4(a5, v5); add4(a6, v6); add4(a7, v7);
    }
    for (; t + slots < hi; t += 2 * slots) {       // 2-deep remainder
        float4 v0 = xb[(size_t)t * 64 + col];
        float4 v1 = xb[(size_t)(t + slots) * 64 + col];
        add4(a0, v0); add4(a1, v1);
    }
    if (t < hi)
        add4(a0, xb[(size_t)t * 64 + col]);

    add4(a0, a1); add4(a2, a3); add4(a4, a5); add4(a6, a7);
    add4(a0, a2); add4(a4, a6); add4(a0, a4);

    __shared__ float4 red[256];        // slots*cols == 256 always
    red[tid] = a0;                     // == red[r*cols + c]
    __syncthreads();
    if (tid < cols) {
        float4 sum = make_float4(0.f, 0.f, 0.f, 0.f);
        for (int rr = 0; rr < slots; ++rr)
            add4(sum, red[rr * cols + tid]);
        sum.x *= inv; sum.y *= inv; sum.z *= inv; sum.w *= inv;
        float4* __restrict__ orow =
            (float4*)(out + ((size_t)b * DST_LEN + jj) * D_AV);
        orow[s * cols + tid] = sum;    // empty window -> exact zeros
    }
}

// Grid (256-thread blocks): [0,NB_COPY) text copy; then audio; then video.
__global__ __launch_bounds__(256)
void fused_align_kernel(const float4* __restrict__ text_in,
                        float4* __restrict__ text_out,
                        const float* __restrict__ audio_x,
                        const float* __restrict__ video_x,
                        const int* __restrict__ text_lengths,
                        const int* __restrict__ audio_lengths,
                        const int* __restrict__ video_lengths,
                        float* __restrict__ out_audio,
                        float* __restrict__ out_video) {
    const int blk = blockIdx.x;
    if (blk < NB_COPY) {
        const int base = blk * 1024 + threadIdx.x;
        #pragma unroll
        for (int k = 0; k < 4; ++k)
            text_out[base + k * 256] = text_in[base + k * 256];
    } else if (blk < NB_COPY + NB_AV) {
        align_row(audio_x, text_lengths, audio_lengths, out_audio,
                  SEQ_A, blk - NB_COPY);
    } else {
        align_row(video_x, text_lengths, video_lengths, out_video,
                  SEQ_V, blk - NB_COPY - NB_AV);
    }
}

extern "C" void kernel_launch(void* const* d_in, const int* in_sizes, int n_in,
                              void* d_out, int out_size, void* d_ws, size_t ws_size,
                              hipStream_t stream) {
    const float* text_x  = (const float*)d_in[0];
    const float* audio_x = (const float*)d_in[1];
    const float* video_x = (const float*)d_in[2];
    const int* text_lengths  = (const int*)d_in[3];
    const int* audio_lengths = (const int*)d_in[4];
    const int* video_lengths = (const int*)d_in[5];

    float* out = (float*)d_out;
    float* out_text  = out;                                        // B*64*768
    float* out_audio = out_text  + (size_t)BATCH * SEQ_T * D_T;    // B*64*256
    float* out_video = out_audio + (size_t)BATCH * DST_LEN * D_AV; // B*64*256

    const int blocks = NB_COPY + 2 * NB_AV;                        // 17,920
    fused_align_kernel<<<blocks, 256, 0, stream>>>(
        (const float4*)text_x, (float4*)out_text,
        audio_x, video_x,
        text_lengths, audio_lengths, video_lengths,
        out_audio, out_video);
}

// Round 7
// 29.404 us; speedup vs baseline: 1.5788x; 1.0534x over previous
//
#include <hip/hip_runtime.h>
#include <hip/hip_bf16.h>

// Sizes from the reference
#define BATCH   128
#define SEQ_T   64
#define SEQ_A   1024
#define SEQ_V   512
#define D_T     768
#define D_AV    256
#define DST_LEN 64

#define NB_COPY 1536   // 1,572,864 float4 / (256 thr * 4 f4)
#define NB_AV   (BATCH * DST_LEN)   // 8192 blocks per modality

__device__ __forceinline__ void add4(float4& a, const float4 v) {
    a.x += v.x; a.y += v.y; a.z += v.z; a.w += v.w;
}

// ---------------------------------------------------------------------------
// One block per (b, j).  For j in [1, ml]: primary block, computes column
// slice 0 of output row j.  For j > ml (normally a zero row): the block first
// writes zeros to its own row j, then — if the sample's windows are large —
// doubles as a helper computing column slice s of row jj, where s=(j-1)/ml,
// jj=j-s*ml.  Slices are disjoint column ranges -> no atomics, no pre-zero.
//   NS=8 (ps>=256):  8 f4 cols x 32 row slots   (ml<=4  -> max j = 32)
//   NS=4 (ps>=128): 16 f4 cols x 16 row slots   (ml<=8  -> max j = 32)
//   NS=2 (ps>=48):  32 f4 cols x  8 row slots   (ml<=21 -> max j = 42)
//   NS=1 (typical): 64 f4 cols x  4 row slots   (full-row bulk path)
// 8 independent accumulators -> 8 loads in flight per thread.
// ---------------------------------------------------------------------------
__device__ __forceinline__ void align_row(const float* __restrict__ x,
                                          const int* __restrict__ text_len,
                                          const int* __restrict__ lengths,
                                          float* __restrict__ out,
                                          int T, int idx) {
    const int b   = idx >> 6;          // 64 rows per sample
    const int j   = idx & 63;
    const int tid = threadIdx.x;

    const int ml  = text_len[b] - 2;   // min_len in [1, 63]
    const int len = lengths[b];

    const unsigned ps = (unsigned)(len + ml - 1) / (unsigned)ml;
    const int k  = (ps >= 256u) ? 3 : (ps >= 128u) ? 2 : (ps >= 48u) ? 1 : 0;
    const int NS = 1 << k;

    int jj, s;
    if (j >= 1 && j <= ml) {
        jj = j; s = 0;                 // primary
    } else {
        // zero own row (row 0 and rows > ml are zero rows)
        if (tid < 64) {
            float4* __restrict__ oz =
                (float4*)(out + ((size_t)b * DST_LEN + j) * D_AV);
            oz[tid] = make_float4(0.f, 0.f, 0.f, 0.f);
        }
        if (j == 0) return;
        s  = (j - 1) / ml;             // >= 1, block-uniform
        jj = j - s * ml;               // 1..ml
        if (s >= NS) return;           // no helper role, block-uniform exit
    }

    const int cols  = 64 >> k;         // f4 columns this block owns
    const int r     = tid >> (6 - k);  // row slot
    const int c     = tid & (cols - 1);
    const int col   = s * cols + c;    // global f4 column
    const int slots = 4 << k;

    const float inv = 1.0f / (float)ps;
    const int lo = (jj - 1) * (int)ps;
    int hi = jj * (int)ps;
    if (hi > len) hi = len;

    const float4* __restrict__ xb =
        (const float4*)(x + (size_t)b * (size_t)T * D_AV);

    float4 a0 = make_float4(0.f, 0.f, 0.f, 0.f);
    float4 a1 = a0, a2 = a0, a3 = a0, a4 = a0, a5 = a0, a6 = a0, a7 = a0;

    int t = lo + r;
    for (; t + 7 * slots < hi; t += 8 * slots) {
        float4 v0 = xb[(size_t)(t            ) * 64 + col];
        float4 v1 = xb[(size_t)(t + 1 * slots) * 64 + col];
        float4 v2 = xb[(size_t)(t + 2 * slots) * 64 + col];
        float4 v3 = xb[(size_t)(t + 3 * slots) * 64 + col];
        float4 v4 = xb[(size_t)(t + 4 * slots) * 64 + col];
        float4 v5 = xb[(size_t)(t + 5 * slots) * 64 + col];
        float4 v6 = xb[(size_t)(t + 6 * slots) * 64 + col];
        float4 v7 = xb[(size_t)(t + 7 * slots) * 64 + col];
        add4(a0, v0); add4(a1, v1); add4(a2, v2); add4(a3, v3);
        add4(a4, v4); add4(a5, v5); add4(a6, v6); add4(a7, v7);
    }
    for (; t + slots < hi; t += 2 * slots) {       // 2-deep remainder
        float4 v0 = xb[(size_t)t * 64 + col];
        float4 v1 = xb[(size_t)(t + slots) * 64 + col];
        add4(a0, v0); add4(a1, v1);
    }
    if (t < hi)
        add4(a0, xb[(size_t)t * 64 + col]);

    add4(a0, a1); add4(a2, a3); add4(a4, a5); add4(a6, a7);
    add4(a0, a2); add4(a4, a6); add4(a0, a4);

    __shared__ float4 red[256];        // slots*cols == 256 always
    red[tid] = a0;                     // == red[r*cols + c]
    __syncthreads();
    if (tid < cols) {
        float4 sum = make_float4(0.f, 0.f, 0.f, 0.f);
        for (int rr = 0; rr < slots; ++rr)
            add4(sum, red[rr * cols + tid]);
        sum.x *= inv; sum.y *= inv; sum.z *= inv; sum.w *= inv;
        float4* __restrict__ orow =
            (float4*)(out + ((size_t)b * DST_LEN + jj) * D_AV);
        orow[s * cols + tid] = sum;    // empty window -> exact zeros
    }
}

// Grid (256-thread blocks): latency-tail align sections FIRST (worst blocks
// start at t=0), pure-BW text copy LAST as filler.
//   [0, NB_AV)        : audio align
//   [NB_AV, 2*NB_AV)  : video align
//   [2*NB_AV, +NB_COPY): text passthrough, 4 float4 per thread
__global__ __launch_bounds__(256)
void fused_align_kernel(const float4* __restrict__ text_in,
                        float4* __restrict__ text_out,
                        const float* __restrict__ audio_x,
                        const float* __restrict__ video_x,
                        const int* __restrict__ text_lengths,
                        const int* __restrict__ audio_lengths,
                        const int* __restrict__ video_lengths,
                        float* __restrict__ out_audio,
                        float* __restrict__ out_video) {
    const int blk = blockIdx.x;
    if (blk < NB_AV) {
        align_row(audio_x, text_lengths, audio_lengths, out_audio,
                  SEQ_A, blk);
    } else if (blk < 2 * NB_AV) {
        align_row(video_x, text_lengths, video_lengths, out_video,
                  SEQ_V, blk - NB_AV);
    } else {
        const int base = (blk - 2 * NB_AV) * 1024 + threadIdx.x;
        #pragma unroll
        for (int k = 0; k < 4; ++k)
            text_out[base + k * 256] = text_in[base + k * 256];
    }
}

extern "C" void kernel_launch(void* const* d_in, const int* in_sizes, int n_in,
                              void* d_out, int out_size, void* d_ws, size_t ws_size,
                              hipStream_t stream) {
    const float* text_x  = (const float*)d_in[0];
    const float* audio_x = (const float*)d_in[1];
    const float* video_x = (const float*)d_in[2];
    const int* text_lengths  = (const int*)d_in[3];
    const int* audio_lengths = (const int*)d_in[4];
    const int* video_lengths = (const int*)d_in[5];

    float* out = (float*)d_out;
    float* out_text  = out;                                        // B*64*768
    float* out_audio = out_text  + (size_t)BATCH * SEQ_T * D_T;    // B*64*256
    float* out_video = out_audio + (size_t)BATCH * DST_LEN * D_AV; // B*64*256

    const int blocks = 2 * NB_AV + NB_COPY;                        // 17,920
    fused_align_kernel<<<blocks, 256, 0, stream>>>(
        (const float4*)text_x, (float4*)out_text,
        audio_x, video_x,
        text_lengths, audio_lengths, video_lengths,
        out_audio, out_video);
}